// Round 2
// baseline (496.719 us; speedup 1.0000x reference)
//
#include <hip/hip_runtime.h>
#include <stdint.h>

// Problem constants (B=8,T=8192,C=256,E=64, top-2, cap_factor=1.25)
#define N_TOK   65536
#define S_SLOTS 131072
#define NEXP    64
#define CDIM    256
#define CAP     2560          // int(1.25 * 131072 / 64)
#define NCHUNK  1024          // 128 slots per chunk (= one gating block)

typedef unsigned short u16;
typedef float    fvec4  __attribute__((ext_vector_type(4)));
typedef float    f32x4  __attribute__((ext_vector_type(4)));
typedef __bf16   bf16x8 __attribute__((ext_vector_type(8)));
typedef unsigned short u16x4 __attribute__((ext_vector_type(4)));

typedef __attribute__((address_space(1))) const void gvoid_t;
typedef __attribute__((address_space(3))) void       svoid_t;

__device__ __forceinline__ u16 f2bf(float f) {          // RNE float->bf16
  uint32_t u = __builtin_bit_cast(uint32_t, f);
  u += 0x7fffu + ((u >> 16) & 1u);
  return (u16)(u >> 16);
}
__device__ __forceinline__ float bf2f(u16 h) {
  return __builtin_bit_cast(float, (uint32_t)h << 16);
}
__device__ __forceinline__ void gload16(const void* g, void* l) {
  __builtin_amdgcn_global_load_lds(
      reinterpret_cast<gvoid_t*>(reinterpret_cast<uintptr_t>(g)),
      reinterpret_cast<svoid_t*>(reinterpret_cast<uintptr_t>(l)),
      16, 0, 0);
}

// ---------------------------------------------------------------------------
// Kernel 1: gating (v3 — barrier-free K-loop, all operands from global).
// 64-token x 64-expert tile, 128 threads (2 waves), grid 1024 (chunk
// granularity & downstream interfaces unchanged). Thread grid 16tx x 8ty,
// MR=8 rows x NR=4 experts = 32 outputs/thread -> 2048 waves = 2/SIMD.
// A: 8 global fvec4 loads/k4, 16-lane broadcast (lanes sharing ty merge).
// B: 4 global fvec4 loads/k4, one contiguous 256B W-row per kk, L1-resident.
// NO LDS in the K-loop -> no barriers -> no vmcnt(0) drains (round-1 lesson).
// Modulo-2 software pipeline: refill a buffer right after its last use;
// issue-to-use distance = one k4 block (~512 cyc) > L2 hit latency.
// x->bf16 conversion interleaved per K-slice (single stream, warms L1/L2).
// Tail: round-1's harness-verified top2/softmax butterfly (4 experts/lane).
// ---------------------------------------------------------------------------
__global__ __launch_bounds__(128) void gating_kernel(
    const float* __restrict__ x, const float* __restrict__ Wg,
    u16* __restrict__ x_bf16, float* __restrict__ slot_score,
    int* __restrict__ slot_eid, float* __restrict__ load_g,
    int* __restrict__ chunk_hist)
{
  __shared__ int   hist_s[64];
  __shared__ float PL[2][64];

  const int t  = threadIdx.x;            // 0..127 (2 waves)
  const int m0 = blockIdx.x * 64;        // token tile base (== chunk id * 64)
  const int tx = t & 15;                 // expert group: e0 = tx*4
  const int ty = t >> 4;                 // row group: rows ty*8 .. +8

  if (t < 64) hist_s[t] = 0;

  const float* pA = x + (size_t)(m0 + ty * 8) * 256;   // 16-lane shared per ty
  const float* pB = Wg + tx * 4;                       // W[k][tx*4..+4]

  float acc[8][4];
#pragma unroll
  for (int j = 0; j < 8; ++j)
#pragma unroll
    for (int i = 0; i < 4; ++i) acc[j][i] = 0.f;

  fvec4 a0[8], a1[8], b0v[4], b1v[4];

#define LOADA(DST, G) { _Pragma("unroll")                                   \
    for (int j = 0; j < 8; ++j)                                             \
      DST[j] = *(const fvec4*)(pA + j * 256 + (G) * 4); }
#define LOADB(DST, G) { _Pragma("unroll")                                   \
    for (int kk = 0; kk < 4; ++kk)                                          \
      DST[kk] = *(const fvec4*)(pB + ((G) * 4 + kk) * 64); }
#define FMAS(AV, BV) { _Pragma("unroll")                                    \
    for (int j = 0; j < 8; ++j) { _Pragma("unroll")                         \
      for (int kk = 0; kk < 4; ++kk) {                                      \
        float a = AV[j][kk];                                                \
        acc[j][0] = fmaf(a, BV[kk][0], acc[j][0]);                          \
        acc[j][1] = fmaf(a, BV[kk][1], acc[j][1]);                          \
        acc[j][2] = fmaf(a, BV[kk][2], acc[j][2]);                          \
        acc[j][3] = fmaf(a, BV[kk][3], acc[j][3]);                          \
      } } }

  LOADA(a0, 0) LOADB(b0v, 0)
  LOADA(a1, 1) LOADB(b1v, 1)

  for (int kt = 0; kt < 8; ++kt) {       // K = 256 in 8 slices of 32
    // ---- x -> bf16 for slice kt (reads the lines A is about to consume;
    //      identical RNE values; coalesced-ish 64B bursts) ----
    {
      int r = t >> 1, c = (t & 1) * 16;
      const float* xs = x + (size_t)(m0 + r) * 256 + kt * 32 + c;
      u16* xd = x_bf16 + (size_t)(m0 + r) * 256 + kt * 32 + c;
#pragma unroll
      for (int q = 0; q < 4; ++q) {
        fvec4 v = *(const fvec4*)(xs + q * 4);
        u16x4 h;
        h.x = f2bf(v.x); h.y = f2bf(v.y); h.z = f2bf(v.z); h.w = f2bf(v.w);
        *(u16x4*)(xd + q * 4) = h;
      }
    }
    // ---- 8 k4 steps; kk4 static after unroll -> buffer parity is static ----
#pragma unroll
    for (int kk4 = 0; kk4 < 8; ++kk4) {
      const int gk4 = kt * 8 + kk4;
      if ((kk4 & 1) == 0) {
        FMAS(a0, b0v)
        if (kt < 7 || kk4 < 6) { LOADA(a0, gk4 + 2) LOADB(b0v, gk4 + 2) }
      } else {
        FMAS(a1, b1v)
        if (kt < 7 || kk4 < 6) { LOADA(a1, gk4 + 2) LOADB(b1v, gk4 + 2) }
      }
    }
  }
#undef LOADA
#undef LOADB
#undef FMAS

  __syncthreads();                       // hist_s init visible before atomics

  // ---- tail: per row j, 16 tx-lanes hold experts tx*4..tx*4+3 ----
  // (value desc, index asc) merge == lax.top_k tie semantics; verified r1.
  const int e0 = tx * 4;
  float pl[4] = {0.f, 0.f, 0.f, 0.f};

#pragma unroll
  for (int j = 0; j < 8; ++j) {
    float v1 = -3.4e38f, v2 = -3.4e38f; int i1 = 0, i2 = 0;
#pragma unroll
    for (int i = 0; i < 4; ++i) {        // local top2 (ascending e, strict >)
      float lg = acc[j][i];
      if (lg > v1)      { v2 = v1; i2 = i1; v1 = lg; i1 = e0 + i; }
      else if (lg > v2) { v2 = lg; i2 = e0 + i; }
    }
#pragma unroll
    for (int off = 1; off < 16; off <<= 1) {   // butterfly over 16 tx-lanes
      float b1 = __shfl_xor(v1, off); int bi1 = __shfl_xor(i1, off);
      float b2 = __shfl_xor(v2, off); int bi2 = __shfl_xor(i2, off);
      bool w1 = (b1 > v1) || (b1 == v1 && bi1 < i1);
      if (w1) {
        bool k2 = (v1 > b2) || (v1 == b2 && i1 < bi2);
        v2 = k2 ? v1 : b2; i2 = k2 ? i1 : bi2;
        v1 = b1; i1 = bi1;
      } else {
        bool k2 = (b1 > v2) || (b1 == v2 && bi1 < i2);
        if (k2) { v2 = b1; i2 = bi1; }
      }
    }
    float mx = v1;                       // top1 IS the row max
    float ex[4]; float s = 0.f;
#pragma unroll
    for (int i = 0; i < 4; ++i) { ex[i] = __expf(acc[j][i] - mx); s += ex[i]; }
#pragma unroll
    for (int off = 1; off < 16; off <<= 1) s += __shfl_xor(s, off);
    float ri = 1.0f / s;
#pragma unroll
    for (int i = 0; i < 4; ++i) pl[i] = fmaf(ex[i], ri, pl[i]);

    if (tx == 0) {
      int tok = m0 + ty * 8 + j;
      slot_eid[2 * tok]     = i1;
      slot_eid[2 * tok + 1] = i2;
      slot_score[2 * tok]     = ri;                  // exp(v1-mx) == 1
      slot_score[2 * tok + 1] = __expf(v2 - mx) * ri;
      atomicAdd(&hist_s[i1], 1);
      atomicAdd(&hist_s[i2], 1);
    }
  }

  // load partials: sum over ty. Within wave: ty&3 via shfl 16,32; then LDS.
#pragma unroll
  for (int i = 0; i < 4; ++i) {
    pl[i] += __shfl_xor(pl[i], 16);
    pl[i] += __shfl_xor(pl[i], 32);
  }
  const int w = t >> 6;
  if ((t & 63) < 16) {
#pragma unroll
    for (int i = 0; i < 4; ++i) PL[w][tx * 4 + i] = pl[i];
  }
  __syncthreads();
  if (t < 64) {
    atomicAdd(&load_g[t], PL[0][t] + PL[1][t]);
    chunk_hist[blockIdx.x * 64 + t] = hist_s[t];
  }
}

// ---------------------------------------------------------------------------
// Kernel 2: W_experts [e][k][d] fp32 -> WT [e][d][k] bf16 (K-fast for MFMA B).
// ---------------------------------------------------------------------------
__global__ __launch_bounds__(256) void wtrans_kernel(
    const float* __restrict__ W, u16* __restrict__ WT)
{
  __shared__ float tile[64 * 65];
  const int b = blockIdx.x;
  const int e = b >> 4, tt = b & 15;
  const int k0 = (tt >> 2) * 64, d0 = (tt & 3) * 64;
  const int t = threadIdx.x;
  const int j = t & 63, i0 = t >> 6;
  const float* We = W + (size_t)e * 65536;
#pragma unroll
  for (int p = 0; p < 16; ++p) {
    int i = p * 4 + i0;
    tile[i * 65 + j] = We[(size_t)(k0 + i) * 256 + d0 + j];   // coalesced on d
  }
  __syncthreads();
  u16* WTe = WT + (size_t)e * 65536;
#pragma unroll
  for (int p = 0; p < 16; ++p) {
    int d = p * 4 + i0;
    WTe[(size_t)(d0 + d) * 256 + k0 + j] = f2bf(tile[j * 65 + d]); // coalesced on k
  }
}

// ---------------------------------------------------------------------------
// Kernel 3a: per-expert exclusive scan over the 1024 chunk histograms.
// ---------------------------------------------------------------------------
__global__ __launch_bounds__(256) void scan_kernel(int* __restrict__ hist)
{
  const int e = blockIdx.x;
  const int t = threadIdx.x;
  const int lane = t & 63, w = t >> 6;
  int h[4];
#pragma unroll
  for (int i = 0; i < 4; ++i) h[i] = hist[(t * 4 + i) * 64 + e];
  int local = h[0] + h[1] + h[2] + h[3];
  int v = local;                         // inclusive wave scan
#pragma unroll
  for (int off = 1; off < 64; off <<= 1) {
    int u = __shfl_up(v, off);
    if (lane >= off) v += u;
  }
  __shared__ int wtot[4];
  if (lane == 63) wtot[w] = v;
  __syncthreads();
  int woff = 0;
  for (int i = 0; i < w; ++i) woff += wtot[i];
  int excl = woff + v - local;
  hist[(t * 4 + 0) * 64 + e] = excl;
  hist[(t * 4 + 1) * 64 + e] = excl + h[0];
  hist[(t * 4 + 2) * 64 + e] = excl + h[0] + h[1];
  hist[(t * 4 + 3) * 64 + e] = excl + h[0] + h[1] + h[2];
}

// ---------------------------------------------------------------------------
// Kernel 3b: rank. 1024 blocks x 128 thr (one slot each). Stable FIFO rank.
// ---------------------------------------------------------------------------
__global__ __launch_bounds__(128) void rank_kernel(
    const int* __restrict__ slot_eid, const int* __restrict__ base,
    int* __restrict__ slot2buf, int* __restrict__ row_token)
{
  const int c = blockIdx.x;
  const int t = threadIdx.x;
  const int s = c * 128 + t;
  const int lane = t & 63, w = t >> 6;
  const int e = slot_eid[s];
  __shared__ int hist0[64];
  if (t < 64) hist0[t] = 0;
  __syncthreads();
  int rank = 0, cnt = 0;
#pragma unroll
  for (int k = 0; k < 64; ++k) {
    int eo = __shfl(e, k);
    bool m = (eo == e);
    rank += (m && k < lane) ? 1 : 0;
    cnt  += m ? 1 : 0;
  }
  if (w == 0 && rank == cnt - 1) hist0[e] = cnt;   // last lane of its expert
  __syncthreads();
  int g = base[c * 64 + e] + rank + (w ? hist0[e] : 0);
  if (g < CAP) {
    slot2buf[s] = e * CAP + g;
    row_token[e * CAP + g] = s >> 1;
  } else {
    slot2buf[s] = -1;                               // capacity-dropped
  }
}

// ---------------------------------------------------------------------------
// Kernel 4: grouped expert GEMM, bf16 MFMA 16x16x32, 128x128 tile, BK=32,
// m97 structure with width-16 global_load_lds; A rows gathered via token ids.
// ---------------------------------------------------------------------------
__global__ __launch_bounds__(256) void gemm_kernel(
    const u16* __restrict__ x_bf16, const u16* __restrict__ WT,
    const int* __restrict__ row_token, u16* __restrict__ y)
{
  __shared__ u16 A_s[128 * 32];
  __shared__ u16 B_s[128 * 32];
  __shared__ int tok_s[128];

  const int b = blockIdx.x;
  const int e = b / 40;
  const int r = b % 40;
  const int m0 = (r >> 1) * 128, n0 = (r & 1) * 128;
  const int t = threadIdx.x;

  if (t < 128) tok_s[t] = row_token[e * CAP + m0 + t];
  __syncthreads();

  const int w = t >> 6, lane = t & 63;
  const int rsub = lane >> 2;
  const int koff = (lane & 3) * 8;

  const int ra0 = w * 32 + rsub;
  const int ra1 = ra0 + 16;
  const char* pa0 = (const char*)(x_bf16 + (size_t)tok_s[ra0] * 256 + koff);
  const char* pa1 = (const char*)(x_bf16 + (size_t)tok_s[ra1] * 256 + koff);
  const u16* WTe = WT + (size_t)e * 65536;
  const char* pb0 = (const char*)(WTe + (size_t)(n0 + ra0) * 256 + koff);
  const char* pb1 = (const char*)(WTe + (size_t)(n0 + ra1) * 256 + koff);

  char* ldsA0 = (char*)A_s + (w * 32) * 64;
  char* ldsA1 = (char*)A_s + (w * 32 + 16) * 64;
  char* ldsB0 = (char*)B_s + (w * 32) * 64;
  char* ldsB1 = (char*)B_s + (w * 32 + 16) * 64;

  const int wm = w & 1, wn = w >> 1;
  const int lr = lane & 15, q = lane >> 4;

  f32x4 acc[4][4];
#pragma unroll
  for (int mt = 0; mt < 4; ++mt)
#pragma unroll
    for (int nt = 0; nt < 4; ++nt) acc[mt][nt] = (f32x4){0.f, 0.f, 0.f, 0.f};

  for (int kt = 0; kt < 8; ++kt) {
    gload16(pa0, ldsA0);
    gload16(pa1, ldsA1);
    gload16(pb0, ldsB0);
    gload16(pb1, ldsB1);
    __syncthreads();
    bf16x8 af[4], bg[4];
#pragma unroll
    for (int mt = 0; mt < 4; ++mt)
      af[mt] = *(const bf16x8*)&A_s[(wm * 64 + mt * 16 + lr) * 32 + q * 8];
#pragma unroll
    for (int nt = 0; nt < 4; ++nt)
      bg[nt] = *(const bf16x8*)&B_s[(wn * 64 + nt * 16 + lr) * 32 + q * 8];
#pragma unroll
    for (int mt = 0; mt < 4; ++mt)
#pragma unroll
      for (int nt = 0; nt < 4; ++nt)
        acc[mt][nt] = __builtin_amdgcn_mfma_f32_16x16x32_bf16(
            af[mt], bg[nt], acc[mt][nt], 0, 0, 0);
    __syncthreads();
    pa0 += 64; pa1 += 64; pb0 += 64; pb1 += 64;
  }

  // C/D layout: col=lane&15, row=quad*4+reg  [verified m89/m91]
  u16* ye = y + (size_t)e * CAP * 256;
#pragma unroll
  for (int mt = 0; mt < 4; ++mt) {
    int grow = m0 + wm * 64 + mt * 16 + q * 4;
#pragma unroll
    for (int nt = 0; nt < 4; ++nt) {
      int gcol = n0 + wn * 64 + nt * 16 + lr;
#pragma unroll
      for (int rr = 0; rr < 4; ++rr)
        ye[(size_t)(grow + rr) * 256 + gcol] = f2bf(acc[mt][nt][rr]);
    }
  }
}

// ---------------------------------------------------------------------------
// Kernel 5: combine. out[t] = s0*y[p0] + s1*y[p1] (dropped -> 0). Wave/token.
// ---------------------------------------------------------------------------
__global__ __launch_bounds__(256) void combine_kernel(
    const u16* __restrict__ y, const int* __restrict__ slot2buf,
    const float* __restrict__ slot_score, float* __restrict__ out)
{
  const int tok  = blockIdx.x * 4 + (threadIdx.x >> 6);
  const int lane = threadIdx.x & 63;
  const int   p0 = slot2buf[2 * tok],   p1 = slot2buf[2 * tok + 1];
  const float s0 = slot_score[2 * tok], s1 = slot_score[2 * tok + 1];
  float o0 = 0.f, o1 = 0.f, o2 = 0.f, o3 = 0.f;
  if (p0 >= 0) {
    u16x4 h = *(const u16x4*)&y[(size_t)p0 * 256 + lane * 4];
    o0 = fmaf(s0, bf2f(h.x), o0); o1 = fmaf(s0, bf2f(h.y), o1);
    o2 = fmaf(s0, bf2f(h.z), o2); o3 = fmaf(s0, bf2f(h.w), o3);
  }
  if (p1 >= 0) {
    u16x4 h = *(const u16x4*)&y[(size_t)p1 * 256 + lane * 4];
    o0 = fmaf(s1, bf2f(h.x), o0); o1 = fmaf(s1, bf2f(h.y), o1);
    o2 = fmaf(s1, bf2f(h.z), o2); o3 = fmaf(s1, bf2f(h.w), o3);
  }
  fvec4 o = {o0, o1, o2, o3};
  *(fvec4*)&out[(size_t)tok * 256 + lane * 4] = o;
}

// ---------------------------------------------------------------------------
// Kernel 6: aux loss = mean((load/N - 1/E)^2). One wave.
// ---------------------------------------------------------------------------
__global__ __launch_bounds__(64) void aux_kernel(
    const float* __restrict__ load_g, float* __restrict__ out_aux)
{
  const int lane = threadIdx.x;
  float l = load_g[lane] * (1.0f / 65536.0f) - (1.0f / 64.0f);
  float v = l * l;
#pragma unroll
  for (int off = 1; off < 64; off <<= 1) v += __shfl_xor(v, off);
  if (lane == 0) out_aux[0] = v * (1.0f / 64.0f);
}

// ---------------------------------------------------------------------------
// Workspace layout (bytes):
//   0        slot_score f32[131072]   (512K)
//   524288   slot_eid   i32[131072]   (512K)
//   1048576  slot2buf   i32[131072]   (512K)
//   1572864  row_token  i32[163840]   (640K)  -- memset 0 each call
//   2228224  load_g     f32[64]               -- memset 0 each call
//   2359296  chunk_hist i32[1024*64]  (256K)  -- fully written by gating
//   4194304  x_bf16     u16[16777216] (32M)
//   37748736 WT         u16[4194304]  (8M)
//   46137344 y          u16[41943040] (80M)
// total ~124 MB
// ---------------------------------------------------------------------------
extern "C" void kernel_launch(void* const* d_in, const int* in_sizes, int n_in,
                              void* d_out, int out_size, void* d_ws, size_t ws_size,
                              hipStream_t stream)
{
  const float* x  = (const float*)d_in[0];
  const float* Wg = (const float*)d_in[1];
  const float* We = (const float*)d_in[2];
  float* out = (float*)d_out;

  char* ws = (char*)d_ws;
  float* slot_score = (float*)(ws + 0);
  int*   slot_eid   = (int*)(ws + 524288);
  int*   slot2buf   = (int*)(ws + 1048576);
  int*   row_token  = (int*)(ws + 1572864);
  float* load_g     = (float*)(ws + 2228224);
  int*   chunk_hist = (int*)(ws + 2359296);
  u16*   x_bf16     = (u16*)(ws + 4194304);
  u16*   WT         = (u16*)(ws + 37748736);
  u16*   y          = (u16*)(ws + 46137344);

  hipMemsetAsync(row_token, 0, 655360, stream);   // unfilled rows -> token 0
  hipMemsetAsync(load_g, 0, 256, stream);

  gating_kernel<<<1024, 128, 0, stream>>>(x, Wg, x_bf16, slot_score, slot_eid,
                                          load_g, chunk_hist);
  wtrans_kernel<<<1024, 256, 0, stream>>>(We, WT);
  scan_kernel<<<64, 256, 0, stream>>>(chunk_hist);
  rank_kernel<<<1024, 128, 0, stream>>>(slot_eid, chunk_hist, slot2buf, row_token);
  gemm_kernel<<<2560, 256, 0, stream>>>(x_bf16, WT, row_token, y);
  combine_kernel<<<16384, 256, 0, stream>>>(y, slot2buf, slot_score, out);
  aux_kernel<<<1, 64, 0, stream>>>(load_g, out + 16777216);
}

// Round 3
// 235.817 us; speedup vs baseline: 2.1064x; 2.1064x over previous
//
#include <hip/hip_runtime.h>
#include <stdint.h>

// Problem constants (B=8,T=8192,C=256,E=64, top-2, cap_factor=1.25)
#define N_TOK   65536
#define S_SLOTS 131072
#define NEXP    64
#define CDIM    256
#define CAP     2560          // int(1.25 * 131072 / 64)
#define NCHUNK  1024          // 128 slots per chunk (= one gating block)

typedef unsigned short u16;
typedef float    fvec4  __attribute__((ext_vector_type(4)));
typedef float    f32x4  __attribute__((ext_vector_type(4)));
typedef __bf16   bf16x8 __attribute__((ext_vector_type(8)));
typedef unsigned short u16x4 __attribute__((ext_vector_type(4)));

typedef __attribute__((address_space(1))) const void gvoid_t;
typedef __attribute__((address_space(3))) void       svoid_t;

__device__ __forceinline__ u16 f2bf(float f) {          // RNE float->bf16
  uint32_t u = __builtin_bit_cast(uint32_t, f);
  u += 0x7fffu + ((u >> 16) & 1u);
  return (u16)(u >> 16);
}
__device__ __forceinline__ float bf2f(u16 h) {
  return __builtin_bit_cast(float, (uint32_t)h << 16);
}
__device__ __forceinline__ void gload16(const void* g, void* l) {
  __builtin_amdgcn_global_load_lds(
      reinterpret_cast<gvoid_t*>(reinterpret_cast<uintptr_t>(g)),
      reinterpret_cast<svoid_t*>(reinterpret_cast<uintptr_t>(l)),
      16, 0, 0);
}

// ---------------------------------------------------------------------------
// Kernel 1: gating. fp32 GEMM (64 tok x 64 exp, K=256) + softmax + top2 +
// x->bf16 conversion + load partials + per-chunk expert histogram.
// (round-0 version, harness-verified at 59 us — restored verbatim after two
//  failed rewrites: r1 = 1 wave/SIMD latency exposure, r2 = VGPR spills.)
// ---------------------------------------------------------------------------
__global__ __launch_bounds__(256) void gating_kernel(
    const float* __restrict__ x, const float* __restrict__ Wg,
    u16* __restrict__ x_bf16, float* __restrict__ slot_score,
    int* __restrict__ slot_eid, float* __restrict__ load_g,
    int* __restrict__ chunk_hist)
{
  __shared__ float smem[8448];       // GEMM: W_s[4096] + A_s[64*68]
  __shared__ int   hist_s[64];       // tail aliases smem (see offsets below)
  float* W_s   = smem;               // [k][e] 64x64
  float* A_s   = smem + 4096;        // [m][k] pitch 68
  float* L_s   = smem;               // [m][e] pitch 65  (tail phase, <=4160)
  float* PMAXs = smem + 4160;        // [w][tok] 4x64
  float* PV1   = smem + 4416;
  int*   PI1   = (int*)(smem + 4672);
  float* PV2   = smem + 4928;
  int*   PI2   = (int*)(smem + 5184);
  float* PSUM  = smem + 5440;
  float* RINVs = smem + 5696;        // [64]
  float* PLOAD = smem + 5760;        // [256]

  const int t  = threadIdx.x;
  const int m0 = blockIdx.x * 64;
  const int ty = t >> 4, tx = t & 15;

  if (t < 64) hist_s[t] = 0;

  float acc[4][4];
#pragma unroll
  for (int j = 0; j < 4; ++j)
#pragma unroll
    for (int i = 0; i < 4; ++i) acc[j][i] = 0.f;

  for (int kt = 0; kt < 4; ++kt) {
    const int k0 = kt * 64;
#pragma unroll
    for (int p = 0; p < 4; ++p) {     // stage W tile [64k][64e]
      int idx = p * 1024 + t * 4;
      int kk = idx >> 6, e = idx & 63;
      *(fvec4*)&W_s[kk * 64 + e] = *(const fvec4*)&Wg[(size_t)(k0 + kk) * 64 + e];
    }
#pragma unroll
    for (int p = 0; p < 4; ++p) {     // stage A tile [64m][64k] + write x_bf16
      int idx = p * 1024 + t * 4;
      int m = idx >> 6, k = idx & 63;
      fvec4 v = *(const fvec4*)&x[(size_t)(m0 + m) * 256 + k0 + k];
      *(fvec4*)&A_s[m * 68 + k] = v;
      u16x4 h;
      h.x = f2bf(v.x); h.y = f2bf(v.y); h.z = f2bf(v.z); h.w = f2bf(v.w);
      *(u16x4*)&x_bf16[(size_t)(m0 + m) * 256 + k0 + k] = h;
    }
    __syncthreads();
#pragma unroll
    for (int k4 = 0; k4 < 16; ++k4) {
      fvec4 av[4], bv[4];
#pragma unroll
      for (int j = 0; j < 4; ++j)
        av[j] = *(const fvec4*)&A_s[(ty * 4 + j) * 68 + k4 * 4];
#pragma unroll
      for (int kk = 0; kk < 4; ++kk)
        bv[kk] = *(const fvec4*)&W_s[(k4 * 4 + kk) * 64 + tx * 4];
#pragma unroll
      for (int j = 0; j < 4; ++j)
#pragma unroll
        for (int i = 0; i < 4; ++i) {
          acc[j][i] = fmaf(av[j][0], bv[0][i], acc[j][i]);
          acc[j][i] = fmaf(av[j][1], bv[1][i], acc[j][i]);
          acc[j][i] = fmaf(av[j][2], bv[2][i], acc[j][i]);
          acc[j][i] = fmaf(av[j][3], bv[3][i], acc[j][i]);
        }
    }
    __syncthreads();                  // also guards L_s alias overwrite below
  }

  // logits -> LDS (pitch 65: column access is bank-conflict-free)
#pragma unroll
  for (int j = 0; j < 4; ++j)
#pragma unroll
    for (int i = 0; i < 4; ++i)
      L_s[(ty * 4 + j) * 65 + tx * 4 + i] = acc[j][i];
  __syncthreads();

  const int w = t >> 6, lane = t & 63;

  // pass1: per-wave partial max + top-2 (on logits; softmax is monotone).
  // Ascending expert order + strict '>' == lowest-index-on-tie (lax.top_k).
  float pm = -3.4e38f, a1 = -3.4e38f, a2 = -3.4e38f;
  int   j1 = 0, j2 = 0;
#pragma unroll
  for (int ii = 0; ii < 16; ++ii) {
    int e = w * 16 + ii;
    float lg = L_s[lane * 65 + e];
    pm = fmaxf(pm, lg);
    if (lg > a1)      { a2 = a1; j2 = j1; a1 = lg; j1 = e; }
    else if (lg > a2) { a2 = lg; j2 = e; }
  }
  PMAXs[w * 64 + lane] = pm;
  PV1[w * 64 + lane] = a1; PI1[w * 64 + lane] = j1;
  PV2[w * 64 + lane] = a2; PI2[w * 64 + lane] = j2;
  __syncthreads();

  // merge the 4 sorted pairs (redundantly in every wave; each needs the max).
  // Current pair always holds LOWER expert indices than the incoming range,
  // so strict '>' on the incoming keeps lowest-index on ties.
  float m  = PMAXs[lane];
  float v1 = PV1[lane]; int i1 = PI1[lane];
  float v2 = PV2[lane]; int i2 = PI2[lane];
#pragma unroll
  for (int ww = 1; ww < 4; ++ww) {
    m = fmaxf(m, PMAXs[ww * 64 + lane]);
    float b1 = PV1[ww * 64 + lane]; int bi1 = PI1[ww * 64 + lane];
    float b2 = PV2[ww * 64 + lane]; int bi2 = PI2[ww * 64 + lane];
    if (b1 > v1) {
      if (v1 >= b2) { v2 = v1; i2 = i1; } else { v2 = b2; i2 = bi2; }
      v1 = b1; i1 = bi1;
    } else if (b1 > v2) { v2 = b1; i2 = bi1; }
  }

  // pass2: E = exp(lg - max) in place (per-wave disjoint columns) + row partial
  float s = 0.f;
#pragma unroll
  for (int ii = 0; ii < 16; ++ii) {
    int e = w * 16 + ii;
    float E = __expf(L_s[lane * 65 + e] - m);
    L_s[lane * 65 + e] = E;
    s += E;
  }
  PSUM[w * 64 + lane] = s;
  __syncthreads();

  if (w == 0) {                       // finalize: scores, ids, chunk histogram
    float rs = PSUM[lane] + PSUM[64 + lane] + PSUM[128 + lane] + PSUM[192 + lane];
    float ri = 1.0f / rs;
    RINVs[lane] = ri;
    float sc1 = L_s[lane * 65 + i1] * ri;
    float sc2 = L_s[lane * 65 + i2] * ri;
    int tg = m0 + lane;
    slot_eid[2 * tg]     = i1;
    slot_eid[2 * tg + 1] = i2;
    slot_score[2 * tg]     = sc1;
    slot_score[2 * tg + 1] = sc2;
    atomicAdd(&hist_s[i1], 1);
    atomicAdd(&hist_s[i2], 1);
  }
  __syncthreads();

  // load partials: thread t covers expert=lane, tokens [w*16, w*16+16)
  {
    float sl = 0.f;
#pragma unroll
    for (int jj = 0; jj < 16; ++jj) {
      int j = w * 16 + jj;
      sl = fmaf(L_s[j * 65 + lane], RINVs[j], sl);
    }
    PLOAD[t] = sl;
  }
  __syncthreads();
  if (t < 64) {
    float sl = PLOAD[t] + PLOAD[64 + t] + PLOAD[128 + t] + PLOAD[192 + t];
    atomicAdd(&load_g[t], sl);
    chunk_hist[blockIdx.x * 64 + t] = hist_s[t];
  }
}

// ---------------------------------------------------------------------------
// Kernel 2: W_experts [e][k][d] fp32 -> WT [e][d][k] bf16 (K-fast for MFMA B).
// ---------------------------------------------------------------------------
__global__ __launch_bounds__(256) void wtrans_kernel(
    const float* __restrict__ W, u16* __restrict__ WT)
{
  __shared__ float tile[64 * 65];
  const int b = blockIdx.x;
  const int e = b >> 4, tt = b & 15;
  const int k0 = (tt >> 2) * 64, d0 = (tt & 3) * 64;
  const int t = threadIdx.x;
  const int j = t & 63, i0 = t >> 6;
  const float* We = W + (size_t)e * 65536;
#pragma unroll
  for (int p = 0; p < 16; ++p) {
    int i = p * 4 + i0;
    tile[i * 65 + j] = We[(size_t)(k0 + i) * 256 + d0 + j];   // coalesced on d
  }
  __syncthreads();
  u16* WTe = WT + (size_t)e * 65536;
#pragma unroll
  for (int p = 0; p < 16; ++p) {
    int d = p * 4 + i0;
    WTe[(size_t)(d0 + d) * 256 + k0 + j] = f2bf(tile[j * 65 + d]); // coalesced on k
  }
}

// ---------------------------------------------------------------------------
// Kernel 3a: per-expert exclusive scan over the 1024 chunk histograms.
// ---------------------------------------------------------------------------
__global__ __launch_bounds__(256) void scan_kernel(int* __restrict__ hist)
{
  const int e = blockIdx.x;
  const int t = threadIdx.x;
  const int lane = t & 63, w = t >> 6;
  int h[4];
#pragma unroll
  for (int i = 0; i < 4; ++i) h[i] = hist[(t * 4 + i) * 64 + e];
  int local = h[0] + h[1] + h[2] + h[3];
  int v = local;                         // inclusive wave scan
#pragma unroll
  for (int off = 1; off < 64; off <<= 1) {
    int u = __shfl_up(v, off);
    if (lane >= off) v += u;
  }
  __shared__ int wtot[4];
  if (lane == 63) wtot[w] = v;
  __syncthreads();
  int woff = 0;
  for (int i = 0; i < w; ++i) woff += wtot[i];
  int excl = woff + v - local;
  hist[(t * 4 + 0) * 64 + e] = excl;
  hist[(t * 4 + 1) * 64 + e] = excl + h[0];
  hist[(t * 4 + 2) * 64 + e] = excl + h[0] + h[1];
  hist[(t * 4 + 3) * 64 + e] = excl + h[0] + h[1] + h[2];
}

// ---------------------------------------------------------------------------
// Kernel 3b: rank. 1024 blocks x 128 thr (one slot each). Stable FIFO rank.
// ---------------------------------------------------------------------------
__global__ __launch_bounds__(128) void rank_kernel(
    const int* __restrict__ slot_eid, const int* __restrict__ base,
    int* __restrict__ slot2buf, int* __restrict__ row_token)
{
  const int c = blockIdx.x;
  const int t = threadIdx.x;
  const int s = c * 128 + t;
  const int lane = t & 63, w = t >> 6;
  const int e = slot_eid[s];
  __shared__ int hist0[64];
  if (t < 64) hist0[t] = 0;
  __syncthreads();
  int rank = 0, cnt = 0;
#pragma unroll
  for (int k = 0; k < 64; ++k) {
    int eo = __shfl(e, k);
    bool m = (eo == e);
    rank += (m && k < lane) ? 1 : 0;
    cnt  += m ? 1 : 0;
  }
  if (w == 0 && rank == cnt - 1) hist0[e] = cnt;   // last lane of its expert
  __syncthreads();
  int g = base[c * 64 + e] + rank + (w ? hist0[e] : 0);
  if (g < CAP) {
    slot2buf[s] = e * CAP + g;
    row_token[e * CAP + g] = s >> 1;
  } else {
    slot2buf[s] = -1;                               // capacity-dropped
  }
}

// ---------------------------------------------------------------------------
// Kernel 4: grouped expert GEMM, bf16 MFMA 16x16x32, 128x128 tile.
// v4: BK=64 (4 K-steps, half the barrier drains of BK=32) + both-sides XOR
// swizzle (rule 21): LDS dest stays linear for global_load_lds; the per-lane
// GLOBAL source is pre-swizzled (chunk c8 ^ (row&7)), and fragment reads
// apply the same XOR ((kk*4+q) ^ (lr&7)). 128B LDS rows without swizzle
// would put all 16 lr-lanes on one 4-bank group (16-way conflict); with it,
// accesses are uniform 8/bank (the b128 minimum). Frags loaded per-kk to
// keep VGPR ~= round-0 (~140).
// ---------------------------------------------------------------------------
__global__ __launch_bounds__(256) void gemm_kernel(
    const u16* __restrict__ x_bf16, const u16* __restrict__ WT,
    const int* __restrict__ row_token, u16* __restrict__ y)
{
  __shared__ u16 A_s[128 * 64];      // [row][64k], row = 128B
  __shared__ u16 B_s[128 * 64];
  __shared__ int tok_s[128];

  const int b = blockIdx.x;
  const int e = b / 40;
  const int r = b % 40;
  const int m0 = (r >> 1) * 128, n0 = (r & 1) * 128;
  const int t = threadIdx.x;

  if (t < 128) tok_s[t] = row_token[e * CAP + m0 + t];
  __syncthreads();

  const int w = t >> 6, lane = t & 63;
  const int rsub8 = lane >> 3;       // row within 8-row group
  const int c8    = lane & 7;        // 16B chunk within 128B row
  const int csw   = (c8 ^ rsub8) * 8;  // swizzled source chunk (u16 units)

  const u16* WTe = WT + (size_t)e * 65536;

  const int wm = w & 1, wn = w >> 1;
  const int lr = lane & 15, q = lane >> 4;

  f32x4 acc[4][4];
#pragma unroll
  for (int mt = 0; mt < 4; ++mt)
#pragma unroll
    for (int nt = 0; nt < 4; ++nt) acc[mt][nt] = (f32x4){0.f, 0.f, 0.f, 0.f};

  for (int kt = 0; kt < 4; ++kt) {
    const int k0 = kt * 64;          // u16 units
    // stage A+B: per wave 4 instrs each, 8 rows x 128B per instr; LDS dest
    // linear (base + lane*16 = row rsub8, chunk c8); source chunk swizzled.
#pragma unroll
    for (int i = 0; i < 4; ++i) {
      int ra = w * 32 + i * 8 + rsub8;
      gload16(x_bf16 + (size_t)tok_s[ra] * 256 + k0 + csw,
              (char*)A_s + (size_t)(w * 32 + i * 8) * 128);
      gload16(WTe + (size_t)(n0 + ra) * 256 + k0 + csw,
              (char*)B_s + (size_t)(w * 32 + i * 8) * 128);
    }
    __syncthreads();
#pragma unroll
    for (int kk = 0; kk < 2; ++kk) {
      bf16x8 af[4], bg[4];
#pragma unroll
      for (int mt = 0; mt < 4; ++mt) {
        int row = wm * 64 + mt * 16 + lr;
        af[mt] = *(const bf16x8*)&A_s[row * 64 + (((kk * 4 + q) ^ (lr & 7)) * 8)];
      }
#pragma unroll
      for (int nt = 0; nt < 4; ++nt) {
        int row = wn * 64 + nt * 16 + lr;
        bg[nt] = *(const bf16x8*)&B_s[row * 64 + (((kk * 4 + q) ^ (lr & 7)) * 8)];
      }
#pragma unroll
      for (int mt = 0; mt < 4; ++mt)
#pragma unroll
        for (int nt = 0; nt < 4; ++nt)
          acc[mt][nt] = __builtin_amdgcn_mfma_f32_16x16x32_bf16(
              af[mt], bg[nt], acc[mt][nt], 0, 0, 0);
    }
    __syncthreads();
  }

  // C/D layout: col=lane&15, row=quad*4+reg  [verified m89/m91]
  u16* ye = y + (size_t)e * CAP * 256;
#pragma unroll
  for (int mt = 0; mt < 4; ++mt) {
    int grow = m0 + wm * 64 + mt * 16 + q * 4;
#pragma unroll
    for (int nt = 0; nt < 4; ++nt) {
      int gcol = n0 + wn * 64 + nt * 16 + lr;
#pragma unroll
      for (int rr = 0; rr < 4; ++rr)
        ye[(size_t)(grow + rr) * 256 + gcol] = f2bf(acc[mt][nt][rr]);
    }
  }
}

// ---------------------------------------------------------------------------
// Kernel 5: combine. out[t] = s0*y[p0] + s1*y[p1] (dropped -> 0). Wave/token.
// ---------------------------------------------------------------------------
__global__ __launch_bounds__(256) void combine_kernel(
    const u16* __restrict__ y, const int* __restrict__ slot2buf,
    const float* __restrict__ slot_score, float* __restrict__ out)
{
  const int tok  = blockIdx.x * 4 + (threadIdx.x >> 6);
  const int lane = threadIdx.x & 63;
  const int   p0 = slot2buf[2 * tok],   p1 = slot2buf[2 * tok + 1];
  const float s0 = slot_score[2 * tok], s1 = slot_score[2 * tok + 1];
  float o0 = 0.f, o1 = 0.f, o2 = 0.f, o3 = 0.f;
  if (p0 >= 0) {
    u16x4 h = *(const u16x4*)&y[(size_t)p0 * 256 + lane * 4];
    o0 = fmaf(s0, bf2f(h.x), o0); o1 = fmaf(s0, bf2f(h.y), o1);
    o2 = fmaf(s0, bf2f(h.z), o2); o3 = fmaf(s0, bf2f(h.w), o3);
  }
  if (p1 >= 0) {
    u16x4 h = *(const u16x4*)&y[(size_t)p1 * 256 + lane * 4];
    o0 = fmaf(s1, bf2f(h.x), o0); o1 = fmaf(s1, bf2f(h.y), o1);
    o2 = fmaf(s1, bf2f(h.z), o2); o3 = fmaf(s1, bf2f(h.w), o3);
  }
  fvec4 o = {o0, o1, o2, o3};
  *(fvec4*)&out[(size_t)tok * 256 + lane * 4] = o;
}

// ---------------------------------------------------------------------------
// Kernel 6: aux loss = mean((load/N - 1/E)^2). One wave.
// ---------------------------------------------------------------------------
__global__ __launch_bounds__(64) void aux_kernel(
    const float* __restrict__ load_g, float* __restrict__ out_aux)
{
  const int lane = threadIdx.x;
  float l = load_g[lane] * (1.0f / 65536.0f) - (1.0f / 64.0f);
  float v = l * l;
#pragma unroll
  for (int off = 1; off < 64; off <<= 1) v += __shfl_xor(v, off);
  if (lane == 0) out_aux[0] = v * (1.0f / 64.0f);
}

// ---------------------------------------------------------------------------
// Workspace layout (bytes):
//   0        slot_score f32[131072]   (512K)
//   524288   slot_eid   i32[131072]   (512K)
//   1048576  slot2buf   i32[131072]   (512K)
//   1572864  row_token  i32[163840]   (640K)  -- memset 0 each call
//   2228224  load_g     f32[64]               -- memset 0 each call
//   2359296  chunk_hist i32[1024*64]  (256K)  -- fully written by gating
//   4194304  x_bf16     u16[16777216] (32M)
//   37748736 WT         u16[4194304]  (8M)
//   46137344 y          u16[41943040] (80M)
// total ~124 MB
// ---------------------------------------------------------------------------
extern "C" void kernel_launch(void* const* d_in, const int* in_sizes, int n_in,
                              void* d_out, int out_size, void* d_ws, size_t ws_size,
                              hipStream_t stream)
{
  const float* x  = (const float*)d_in[0];
  const float* Wg = (const float*)d_in[1];
  const float* We = (const float*)d_in[2];
  float* out = (float*)d_out;

  char* ws = (char*)d_ws;
  float* slot_score = (float*)(ws + 0);
  int*   slot_eid   = (int*)(ws + 524288);
  int*   slot2buf   = (int*)(ws + 1048576);
  int*   row_token  = (int*)(ws + 1572864);
  float* load_g     = (float*)(ws + 2228224);
  int*   chunk_hist = (int*)(ws + 2359296);
  u16*   x_bf16     = (u16*)(ws + 4194304);
  u16*   WT         = (u16*)(ws + 37748736);
  u16*   y          = (u16*)(ws + 46137344);

  hipMemsetAsync(row_token, 0, 655360, stream);   // unfilled rows -> token 0
  hipMemsetAsync(load_g, 0, 256, stream);

  gating_kernel<<<1024, 256, 0, stream>>>(x, Wg, x_bf16, slot_score, slot_eid,
                                          load_g, chunk_hist);
  wtrans_kernel<<<1024, 256, 0, stream>>>(We, WT);
  scan_kernel<<<64, 256, 0, stream>>>(chunk_hist);
  rank_kernel<<<1024, 128, 0, stream>>>(slot_eid, chunk_hist, slot2buf, row_token);
  gemm_kernel<<<2560, 256, 0, stream>>>(x_bf16, WT, row_token, y);
  combine_kernel<<<16384, 256, 0, stream>>>(y, slot2buf, slot_score, out);
  aux_kernel<<<1, 64, 0, stream>>>(load_g, out + 16777216);
}